// Round 1
// baseline (9.752 us; speedup 1.0000x reference)
//
#include <hip/hip_runtime.h>

#define BATCH 64
#define MAX_CONTEXT_LEN 32768

// Ragged gather:
//   for b in [0,64): out[kv_indptr[b] : kv_indptr[b+1]] =
//       req_to_token[req_pool_indices[b], kv_start_idx[b] : kv_start_idx[b]+len_b]
// Flat decomposition: one thread per output element, binary-search kv_indptr
// (65 ints, staged in LDS) to find the owning request. Reads within a request
// are contiguous columns of one row -> coalesced; writes are flat -> coalesced.
__global__ void ragged_gather_kernel(const int* __restrict__ req_to_token,
                                     const int* __restrict__ req_pool_indices,
                                     const int* __restrict__ kv_indptr,
                                     const int* __restrict__ kv_start_idx,
                                     int* __restrict__ out,
                                     int total) {
    __shared__ int s_indptr[BATCH + 1];
    __shared__ int s_row[BATCH];
    __shared__ int s_start[BATCH];

    if (threadIdx.x < BATCH + 1) s_indptr[threadIdx.x] = kv_indptr[threadIdx.x];
    if (threadIdx.x < BATCH) {
        s_row[threadIdx.x]   = req_pool_indices[threadIdx.x];
        s_start[threadIdx.x] = kv_start_idx[threadIdx.x];
    }
    __syncthreads();

    int pos = blockIdx.x * blockDim.x + threadIdx.x;
    if (pos >= total) return;

    // find req such that s_indptr[req] <= pos < s_indptr[req+1]
    int lo = 0, hi = BATCH;           // invariant: s_indptr[lo] <= pos < s_indptr[hi]
    #pragma unroll
    for (int it = 0; it < 6; ++it) {  // log2(64) = 6 steps
        int mid = (lo + hi) >> 1;
        if (s_indptr[mid] <= pos) lo = mid; else hi = mid;
    }
    int req = lo;
    int off = pos - s_indptr[req];
    long long row = (long long)s_row[req];
    int col = s_start[req] + off;
    out[pos] = req_to_token[row * (long long)MAX_CONTEXT_LEN + (long long)col];
}

extern "C" void kernel_launch(void* const* d_in, const int* in_sizes, int n_in,
                              void* d_out, int out_size, void* d_ws, size_t ws_size,
                              hipStream_t stream) {
    const int* req_to_token     = (const int*)d_in[0];
    const int* req_pool_indices = (const int*)d_in[1];
    // d_in[2] = page_kernel_lens (unused; kv_indptr already encodes it)
    const int* kv_indptr        = (const int*)d_in[3];
    const int* kv_start_idx     = (const int*)d_in[4];
    int* out = (int*)d_out;

    if (out_size <= 0) return;
    const int block = 256;
    const int grid = (out_size + block - 1) / block;
    ragged_gather_kernel<<<grid, block, 0, stream>>>(
        req_to_token, req_pool_indices, kv_indptr, kv_start_idx, out, out_size);
}